// Round 5
// baseline (4018.814 us; speedup 1.0000x reference)
//
#include <hip/hip_runtime.h>
#include <math.h>

// Problem constants (fixed by setup_inputs)
#define BB 8
#define NN 2048
#define HH 128
#define NSEG 8             // j-segments per node (256 j's each)
#define SEGJ 256
#define SEGCAP 12          // capacity per segment (Poisson mean ~1.1/seg)
#define MAXNBR (NSEG*SEGCAP)  // 96 per node
#define PREDL 10
#define TSTRIDE (NN*3)
#define OUT_BSTRIDE ((PREDL+1)*NN*3)
#define NBLK 512

// Union LDS: adjacency phase needs 39.9 KB, dense phases need 49.7 KB.
union SMemU {
    struct {
        float4 pos[NN];                  // 32 KiB
        unsigned short jb[256][SEGCAP];  // 6 KiB
        int degs[256];                   // 1 KiB
    } adj;
    struct {
        float uS[32][HH + 4];            // 16.9 KiB
        float wS[2][32 * HH];            // 32 KiB
    } g;
};

// ---------------------------------------------------------------------------
// Manual device-scope grid barrier (no cooperative API).
// bar[0],bar[1] = ping-pong arrival counters; bar[2] = generation.
// Requires all NBLK blocks co-resident: __launch_bounds__(256,2) => 2
// blocks/CU, 256 CU x 2 = 512 = NBLK; LDS 49.7KB x 2 = 99.4 <= 160 KB.
// ---------------------------------------------------------------------------
__device__ __forceinline__ void grid_barrier(unsigned* bar, unsigned& gen) {
    __syncthreads();
    if (threadIdx.x == 0) {
        __threadfence();   // make this block's global writes visible device-wide
        const unsigned g = gen;
        const unsigned idx = g & 1u;
        unsigned arrived = __hip_atomic_fetch_add(&bar[idx], 1u,
                              __ATOMIC_ACQ_REL, __HIP_MEMORY_SCOPE_AGENT);
        if (arrived == NBLK - 1u) {
            // reset this counter (reused at gen g+2; visibility carried by the
            // release below + the g+1 release), then release everyone.
            __hip_atomic_store(&bar[idx], 0u, __ATOMIC_RELAXED,
                               __HIP_MEMORY_SCOPE_AGENT);
            __hip_atomic_fetch_add(&bar[2], 1u, __ATOMIC_ACQ_REL,
                                   __HIP_MEMORY_SCOPE_AGENT);
        } else {
            while (__hip_atomic_load(&bar[2], __ATOMIC_ACQUIRE,
                                     __HIP_MEMORY_SCOPE_AGENT) == g)
                __builtin_amdgcn_s_sleep(2);
        }
        gen = g + 1u;
    }
    __syncthreads();
}

// Zero barrier state each call (ws is re-poisoned to 0xAA before every launch).
__global__ void k_bar_init(unsigned* bar) {
    if (threadIdx.x < 4) bar[threadIdx.x] = 0u;
}

// ---------------------------------------------------------------------------
// Gather u-tile (pre-scaled rows, compacted neighbor list) into LDS.
// Verbatim from R3 (same FP order).
// ---------------------------------------------------------------------------
__device__ __forceinline__ void gather_into_lds(const float* __restrict__ xin,
                                                const float* __restrict__ dinv,
                                                const int* __restrict__ nbr,
                                                const int* __restrict__ cntN,
                                                int b, int tile,
                                                float (*uS)[HH + 4]) {
    const int node = threadIdx.x >> 3;   // 0..31
    const int part = threadIdx.x & 7;    // 16 ch each
    const int i = tile * 32 + node;
    const int gi = b * NN + i;
    const int c0 = part * 16;
    float acc[16];
    const float* xs = xin + (size_t)gi * HH + c0;
#pragma unroll
    for (int r = 0; r < 4; ++r) *(float4*)&acc[r * 4] = *(const float4*)(xs + r * 4);
    const int cnt = cntN[gi];
    const int* nb = nbr + gi * MAXNBR;
    for (int k = 0; k < cnt; ++k) {
        const int j = nb[k];
        const float* xr = xin + (size_t)(b * NN + j) * HH + c0;
#pragma unroll
        for (int r = 0; r < 4; ++r) {
            float v[4];
            *(float4*)v = *(const float4*)(xr + r * 4);
            acc[r * 4 + 0] += v[0]; acc[r * 4 + 1] += v[1];
            acc[r * 4 + 2] += v[2]; acc[r * 4 + 3] += v[3];
        }
    }
    const float di = dinv[gi];
#pragma unroll
    for (int r = 0; r < 4; ++r) {
        float4 o;
        o.x = acc[r * 4 + 0] * di; o.y = acc[r * 4 + 1] * di;
        o.z = acc[r * 4 + 2] * di; o.w = acc[r * 4 + 3] * di;
        *(float4*)&uS[node][c0 + r * 4] = o;
    }
}

// GEMM over one 32-row W panel held in LDS. Thread owns 2 nodes x 8 ch.
__device__ __forceinline__ void gemm_panel(const float (*uS)[HH + 4],
                                           const float* __restrict__ wbuf,
                                           int p, int n0, int cc0,
                                           float y0[8], float y1[8]) {
#pragma unroll 2
    for (int r = 0; r < 32; r += 4) {
        float ua[4], ub[4];
        *(float4*)ua = *(const float4*)(&uS[n0][p * 32 + r]);
        *(float4*)ub = *(const float4*)(&uS[n0 + 1][p * 32 + r]);
        const float* wrow = wbuf + r * HH + cc0;
#pragma unroll
        for (int q = 0; q < 4; ++q) {
            float4 wa = *(const float4*)(wrow + q * HH);
            float4 wb = *(const float4*)(wrow + q * HH + 4);
            float u0 = ua[q], u1 = ub[q];
            y0[0] = fmaf(u0, wa.x, y0[0]); y0[1] = fmaf(u0, wa.y, y0[1]);
            y0[2] = fmaf(u0, wa.z, y0[2]); y0[3] = fmaf(u0, wa.w, y0[3]);
            y0[4] = fmaf(u0, wb.x, y0[4]); y0[5] = fmaf(u0, wb.y, y0[5]);
            y0[6] = fmaf(u0, wb.z, y0[6]); y0[7] = fmaf(u0, wb.w, y0[7]);
            y1[0] = fmaf(u1, wa.x, y1[0]); y1[1] = fmaf(u1, wa.y, y1[1]);
            y1[2] = fmaf(u1, wa.z, y1[2]); y1[3] = fmaf(u1, wa.w, y1[3]);
            y1[4] = fmaf(u1, wb.x, y1[4]); y1[5] = fmaf(u1, wb.y, y1[5]);
            y1[6] = fmaf(u1, wb.z, y1[6]); y1[7] = fmaf(u1, wb.w, y1[7]);
        }
    }
}

// ---------------------------------------------------------------------------
// Mega-kernel: INIT + 10 x (ADJ -> L0 -> MID -> LAST), manual grid barrier
// between phases. Phase bodies verbatim from R3 (same FP order -> output
// bit-identical to R3's 0.03125 absmax).
// ---------------------------------------------------------------------------
__global__ __launch_bounds__(256, 2) void k_mega(
    const float* __restrict__ points, const float* __restrict__ padding,
    const float* __restrict__ W0, const float* __restrict__ b0,
    const float* __restrict__ W1, const float* __restrict__ b1,
    const float* __restrict__ W2, const float* __restrict__ b2,
    const float* __restrict__ Wfc, const float* __restrict__ bfc,
    float* __restrict__ out, float* __restrict__ states,
    float* __restrict__ xs0, float* __restrict__ xs1, float* __restrict__ xs2,
    float* __restrict__ dinv, int* __restrict__ nbr, int* __restrict__ cntN,
    unsigned* __restrict__ bar)
{
    __shared__ SMemU sm;
    const int tid = threadIdx.x;
    const int bid = blockIdx.x;
    const int b = bid & 7;       // XCD-friendly batch split
    const int tile = bid >> 3;   // 0..63 (32 nodes each)
    unsigned gen = 0;

    // ---- INIT: states0 = [points, 0]; t=0 output slice ----
    if (tid < 32) {
        int idx = bid * 32 + tid;
        int ib = idx >> 11;
        int n = idx & 2047;
        float px = points[idx * 3 + 0];
        float py = points[idx * 3 + 1];
        float pz = points[idx * 3 + 2];
        float* s = states + (size_t)idx * 6;
        s[0] = px; s[1] = py; s[2] = pz; s[3] = 0.f; s[4] = 0.f; s[5] = 0.f;
        float* o = out + (size_t)ib * OUT_BSTRIDE + n * 3;
        o[0] = px; o[1] = py; o[2] = pz;
    }
    grid_barrier(bar, gen);

    for (int step = 0; step < PREDL; ++step) {
        // ================= ADJ =================
        {
            const float R2c = 0.01f;
            const float* sb = states + (size_t)b * NN * 6;
            for (int j = tid; j < NN; j += 256) {
                const float* r = sb + j * 6;
                sm.adj.pos[j] = make_float4(r[0], r[1], r[2], 0.f);
            }
            __syncthreads();
            int node = tid & 31;
            int seg  = tid >> 5;     // 0..7
            int i = tile * 32 + node;
            int gi = b * NN + i;
            float4 pi = sm.adj.pos[i];
            int cnt = 0;
            int j0 = seg * SEGJ;
#pragma unroll 4
            for (int j = j0; j < j0 + SEGJ; ++j) {
                float4 pj = sm.adj.pos[j];
                float dx = pi.x - pj.x;
                float dy = pi.y - pj.y;
                float dz = pi.z - pj.z;
                // exact np order: (dx*dx + dy*dy) + dz*dz, no fma contraction
                float d2 = __fadd_rn(__fadd_rn(__fmul_rn(dx, dx), __fmul_rn(dy, dy)),
                                     __fmul_rn(dz, dz));
                if (d2 < R2c && j != i) {
                    if (cnt < SEGCAP) sm.adj.jb[tid][cnt] = (unsigned short)j;
                    cnt++;
                }
            }
            if (cnt > SEGCAP) cnt = SEGCAP;
            sm.adj.degs[tid] = cnt;
            __syncthreads();
            int off = 0;
            for (int s = 0; s < seg; ++s) off += sm.adj.degs[s * 32 + node];
            int base = gi * MAXNBR + off;
            for (int k = 0; k < cnt; ++k) nbr[base + k] = (int)sm.adj.jb[tid][k];
            if (seg == NSEG - 1) {
                int tot = off + cnt;
                cntN[gi] = tot;
                float di = (float)(1.0 / sqrt((double)(1 + tot)));  // exact rsqrt
                dinv[gi] = di;
                const float* srow = sb + (size_t)i * 6;
                float* xr = xs0 + (size_t)gi * 6;
#pragma unroll
                for (int c = 0; c < 6; ++c) xr[c] = di * srow[c];
            }
        }
        grid_barrier(bar, gen);

        // ================= L0 (6 -> 128) =================
        {
            int node = tid >> 3;
            int part = tid & 7;
            int i = tile * 32 + node;
            int gi = b * NN + i;
            float g[6];
            {
                const float* sr = xs0 + (size_t)gi * 6;
                float2 a0 = *(const float2*)sr;
                float2 a1 = *(const float2*)(sr + 2);
                float2 a2 = *(const float2*)(sr + 4);
                g[0] = a0.x; g[1] = a0.y; g[2] = a1.x;
                g[3] = a1.y; g[4] = a2.x; g[5] = a2.y;
            }
            int cnt = cntN[gi];
            const int* nb = nbr + gi * MAXNBR;
            for (int k = 0; k < cnt; ++k) {
                int j = nb[k];
                const float* xr = xs0 + (size_t)(b * NN + j) * 6;
                float2 v0 = *(const float2*)xr;
                float2 v1 = *(const float2*)(xr + 2);
                float2 v2 = *(const float2*)(xr + 4);
                g[0] += v0.x; g[1] += v0.y; g[2] += v1.x;
                g[3] += v1.y; g[4] += v2.x; g[5] += v2.y;
            }
            float di = dinv[gi];
#pragma unroll
            for (int c = 0; c < 6; ++c) g[c] *= di;
            int c0 = part * 16;
            float y[16];
#pragma unroll
            for (int r = 0; r < 4; ++r) {
                float4 bv = *(const float4*)(b0 + c0 + r * 4);
                y[r * 4 + 0] = bv.x; y[r * 4 + 1] = bv.y;
                y[r * 4 + 2] = bv.z; y[r * 4 + 3] = bv.w;
            }
#pragma unroll
            for (int k = 0; k < 6; ++k) {
                float u = g[k];
                const float* wr = W0 + k * HH + c0;
#pragma unroll
                for (int r = 0; r < 4; ++r) {
                    float4 w = *(const float4*)(wr + r * 4);
                    y[r * 4 + 0] = fmaf(u, w.x, y[r * 4 + 0]);
                    y[r * 4 + 1] = fmaf(u, w.y, y[r * 4 + 1]);
                    y[r * 4 + 2] = fmaf(u, w.z, y[r * 4 + 2]);
                    y[r * 4 + 3] = fmaf(u, w.w, y[r * 4 + 3]);
                }
            }
            float* xo = xs1 + (size_t)gi * HH + c0;
#pragma unroll
            for (int r = 0; r < 4; ++r) {
                float4 v;
                v.x = di * fmaxf(y[r * 4 + 0], 0.f);
                v.y = di * fmaxf(y[r * 4 + 1], 0.f);
                v.z = di * fmaxf(y[r * 4 + 2], 0.f);
                v.w = di * fmaxf(y[r * 4 + 3], 0.f);
                *(float4*)(xo + r * 4) = v;
            }
        }
        grid_barrier(bar, gen);

        // ================= MID (layer 1, 128 -> 128) =================
        {
            const float4* Wf4 = (const float4*)W1;
            float4 wreg[4];
#pragma unroll
            for (int q = 0; q < 4; ++q) wreg[q] = Wf4[tid + q * 256];   // panel 0
            gather_into_lds(xs1, dinv, nbr, cntN, b, tile, sm.g.uS);
            {
                float4* ws4 = (float4*)sm.g.wS[0];
#pragma unroll
                for (int q = 0; q < 4; ++q) ws4[tid + q * 256] = wreg[q];
            }
            __syncthreads();
            int cb = tid & 15, ng = tid >> 4;
            int n0 = ng * 2, cc0 = cb * 8;
            float y0[8], y1[8];
            {
                float4 bv0 = *(const float4*)(b1 + cc0);
                float4 bv1 = *(const float4*)(b1 + cc0 + 4);
                y0[0] = bv0.x; y0[1] = bv0.y; y0[2] = bv0.z; y0[3] = bv0.w;
                y0[4] = bv1.x; y0[5] = bv1.y; y0[6] = bv1.z; y0[7] = bv1.w;
#pragma unroll
                for (int r = 0; r < 8; ++r) y1[r] = y0[r];
            }
#pragma unroll
            for (int p = 0; p < 4; ++p) {
                if (p < 3) {
#pragma unroll
                    for (int q = 0; q < 4; ++q) wreg[q] = Wf4[(p + 1) * 1024 + tid + q * 256];
                }
                gemm_panel(sm.g.uS, sm.g.wS[p & 1], p, n0, cc0, y0, y1);
                if (p < 3) {
                    float4* ws4 = (float4*)sm.g.wS[1 - (p & 1)];
#pragma unroll
                    for (int q = 0; q < 4; ++q) ws4[tid + q * 256] = wreg[q];
                    __syncthreads();
                }
            }
            int g0 = b * NN + tile * 32 + n0;
            float di0 = dinv[g0], di1 = dinv[g0 + 1];
            float* o0 = xs2 + (size_t)g0 * HH + cc0;
            float* o1 = o0 + HH;
            float4 va, vb;
            va.x = di0 * fmaxf(y0[0], 0.f); va.y = di0 * fmaxf(y0[1], 0.f);
            va.z = di0 * fmaxf(y0[2], 0.f); va.w = di0 * fmaxf(y0[3], 0.f);
            vb.x = di0 * fmaxf(y0[4], 0.f); vb.y = di0 * fmaxf(y0[5], 0.f);
            vb.z = di0 * fmaxf(y0[6], 0.f); vb.w = di0 * fmaxf(y0[7], 0.f);
            *(float4*)o0 = va; *(float4*)(o0 + 4) = vb;
            va.x = di1 * fmaxf(y1[0], 0.f); va.y = di1 * fmaxf(y1[1], 0.f);
            va.z = di1 * fmaxf(y1[2], 0.f); va.w = di1 * fmaxf(y1[3], 0.f);
            vb.x = di1 * fmaxf(y1[4], 0.f); vb.y = di1 * fmaxf(y1[5], 0.f);
            vb.z = di1 * fmaxf(y1[6], 0.f); vb.w = di1 * fmaxf(y1[7], 0.f);
            *(float4*)o1 = va; *(float4*)(o1 + 4) = vb;
        }
        grid_barrier(bar, gen);

        // ================= LAST (layer 2 + FC + state update) =================
        {
            const float4* Wf4 = (const float4*)W2;
            float4 wreg[4];
#pragma unroll
            for (int q = 0; q < 4; ++q) wreg[q] = Wf4[tid + q * 256];
            gather_into_lds(xs2, dinv, nbr, cntN, b, tile, sm.g.uS);
            {
                float4* ws4 = (float4*)sm.g.wS[0];
#pragma unroll
                for (int q = 0; q < 4; ++q) ws4[tid + q * 256] = wreg[q];
            }
            __syncthreads();
            int cb = tid & 15, ng = tid >> 4;
            int n0 = ng * 2, cc0 = cb * 8;
            float y0[8], y1[8];
            {
                float4 bv0 = *(const float4*)(b2 + cc0);
                float4 bv1 = *(const float4*)(b2 + cc0 + 4);
                y0[0] = bv0.x; y0[1] = bv0.y; y0[2] = bv0.z; y0[3] = bv0.w;
                y0[4] = bv1.x; y0[5] = bv1.y; y0[6] = bv1.z; y0[7] = bv1.w;
#pragma unroll
                for (int r = 0; r < 8; ++r) y1[r] = y0[r];
            }
#pragma unroll
            for (int p = 0; p < 4; ++p) {
                if (p < 3) {
#pragma unroll
                    for (int q = 0; q < 4; ++q) wreg[q] = Wf4[(p + 1) * 1024 + tid + q * 256];
                }
                gemm_panel(sm.g.uS, sm.g.wS[p & 1], p, n0, cc0, y0, y1);
                if (p < 3) {
                    float4* ws4 = (float4*)sm.g.wS[1 - (p & 1)];
#pragma unroll
                    for (int q = 0; q < 4; ++q) ws4[tid + q * 256] = wreg[q];
                    __syncthreads();
                }
            }
            __syncthreads();   // all panel reads done; reuse wS
            float* y3  = sm.g.wS[0];   // [32][HH]
            float* wfc = sm.g.wS[1];   // HH*6 floats
#pragma unroll
            for (int q = 0; q < 3; ++q) wfc[tid + q * 256] = Wfc[tid + q * 256];
            {
                float4 v;
                v.x = fmaxf(y0[0], 0.f); v.y = fmaxf(y0[1], 0.f);
                v.z = fmaxf(y0[2], 0.f); v.w = fmaxf(y0[3], 0.f);
                *(float4*)&y3[n0 * HH + cc0] = v;
                v.x = fmaxf(y0[4], 0.f); v.y = fmaxf(y0[5], 0.f);
                v.z = fmaxf(y0[6], 0.f); v.w = fmaxf(y0[7], 0.f);
                *(float4*)&y3[n0 * HH + cc0 + 4] = v;
                v.x = fmaxf(y1[0], 0.f); v.y = fmaxf(y1[1], 0.f);
                v.z = fmaxf(y1[2], 0.f); v.w = fmaxf(y1[3], 0.f);
                *(float4*)&y3[(n0 + 1) * HH + cc0] = v;
                v.x = fmaxf(y1[4], 0.f); v.y = fmaxf(y1[5], 0.f);
                v.z = fmaxf(y1[6], 0.f); v.w = fmaxf(y1[7], 0.f);
                *(float4*)&y3[(n0 + 1) * HH + cc0 + 4] = v;
            }
            __syncthreads();
            if (tid < 192) {
                int n = tid / 6;
                int c = tid - n * 6;
                float r = bfc[c];
                for (int k = 0; k < HH; k += 4) {
                    float yv[4];
                    *(float4*)yv = *(const float4*)&y3[n * HH + k];
                    r = fmaf(yv[0], wfc[(k + 0) * 6 + c], r);
                    r = fmaf(yv[1], wfc[(k + 1) * 6 + c], r);
                    r = fmaf(yv[2], wfc[(k + 2) * 6 + c], r);
                    r = fmaf(yv[3], wfc[(k + 3) * 6 + c], r);
                }
                int i = tile * 32 + n;
                int gi = b * NN + i;
                float pv = padding[b * NN + i];   // all-ones in this setup
                float s = states[(size_t)gi * 6 + c] + r * pv;
                states[(size_t)gi * 6 + c] = s;
                float* outt = out + (size_t)(step + 1) * TSTRIDE;
                if (c < 3) outt[(size_t)b * OUT_BSTRIDE + i * 3 + c] = s;
            }
        }
        grid_barrier(bar, gen);
    }
}

// ---------------------------------------------------------------------------
extern "C" void kernel_launch(void* const* d_in, const int* in_sizes, int n_in,
                              void* d_out, int out_size, void* d_ws, size_t ws_size,
                              hipStream_t stream) {
    (void)in_sizes; (void)n_in; (void)out_size; (void)ws_size;
    const float* points  = (const float*)d_in[0];
    const float* padding = (const float*)d_in[5];
    const float* W0  = (const float*)d_in[6];
    const float* b0  = (const float*)d_in[7];
    const float* W1  = (const float*)d_in[8];
    const float* b1  = (const float*)d_in[9];
    const float* W2  = (const float*)d_in[10];
    const float* b2  = (const float*)d_in[11];
    const float* Wfc = (const float*)d_in[12];
    const float* bfc = (const float*)d_in[13];
    float* out = (float*)d_out;

    // workspace carve-up (~24 MB)
    float* ws     = (float*)d_ws;
    float* states = ws;                       // BB*NN*6
    float* xs0    = states + BB * NN * 6;     // BB*NN*6
    float* xs1    = xs0 + BB * NN * 6;        // BB*NN*HH
    float* xs2    = xs1 + BB * NN * HH;       // BB*NN*HH
    float* dinvp  = xs2 + BB * NN * HH;       // BB*NN
    int*   nbr    = (int*)(dinvp + BB * NN);  // BB*NN*MAXNBR
    int*   cntN   = nbr + BB * NN * MAXNBR;   // BB*NN
    unsigned* bar = (unsigned*)(cntN + BB * NN); // 4 words barrier state

    k_bar_init<<<1, 64, 0, stream>>>(bar);
    k_mega<<<NBLK, 256, 0, stream>>>(points, padding, W0, b0, W1, b1,
                                     W2, b2, Wfc, bfc, out, states,
                                     xs0, xs1, xs2, dinvp, nbr, cntN, bar);
}

// Round 6
// 796.771 us; speedup vs baseline: 5.0439x; 5.0439x over previous
//
#include <hip/hip_runtime.h>
#include <math.h>

// Problem constants (fixed by setup_inputs)
#define BB 8
#define NN 2048
#define HH 128
#define NSEG 8             // j-segments per node (256 j's each)
#define SEGJ 256
#define SEGCAP 12          // capacity per segment (Poisson mean ~1.1/seg)
#define MAXNBR (NSEG*SEGCAP)  // 96 per node
#define PREDL 10
#define TSTRIDE (NN*3)
#define OUT_BSTRIDE ((PREDL+1)*NN*3)

// ---------------------------------------------------------------------------
// K0: states0 = [points, 0]; write t=0 output slice
// ---------------------------------------------------------------------------
__global__ __launch_bounds__(256) void k_init(const float* __restrict__ points,
                                              float* __restrict__ states,
                                              float* __restrict__ out) {
    int idx = blockIdx.x * 256 + threadIdx.x;
    if (idx >= BB * NN) return;
    int b = idx >> 11;
    int n = idx & 2047;
    float px = points[idx * 3 + 0];
    float py = points[idx * 3 + 1];
    float pz = points[idx * 3 + 2];
    float* s = states + (size_t)idx * 6;
    s[0] = px; s[1] = py; s[2] = pz; s[3] = 0.f; s[4] = 0.f; s[5] = 0.f;
    float* o = out + (size_t)b * OUT_BSTRIDE + n * 3;
    o[0] = px; o[1] = py; o[2] = pz;
}

// ---------------------------------------------------------------------------
// K1: radius-graph + compacted flat neighbor list (ascending j). d2 in
// numpy's exact rounding order (no fma) -> step-1 adjacency bit-exact.
// Lane map: node = tid&31, seg = tid>>5 (pos[j] reads <=2 distinct LDS
// addrs per wave = conflict-free).
// ---------------------------------------------------------------------------
__global__ __launch_bounds__(256, 2) void k_adj(const float* __restrict__ states,
                                                float* __restrict__ xs0,
                                                float* __restrict__ dinv,
                                                int* __restrict__ nbr,
                                                int* __restrict__ cntN) {
    const float R2c = 0.01f;
    int b = blockIdx.x & 7;
    int tile = blockIdx.x >> 3;
    __shared__ float4 pos[NN];                  // 32 KiB
    __shared__ int degs[256];                   // 1 KiB
    __shared__ unsigned short jb[256][SEGCAP];  // 6 KiB
    const float* sb = states + (size_t)b * NN * 6;
    for (int j = threadIdx.x; j < NN; j += 256) {
        const float* r = sb + j * 6;
        pos[j] = make_float4(r[0], r[1], r[2], 0.f);
    }
    __syncthreads();
    int node = threadIdx.x & 31;
    int seg  = threadIdx.x >> 5;     // 0..7
    int i = tile * 32 + node;
    int gi = b * NN + i;
    float4 pi = pos[i];
    int cnt = 0;
    int j0 = seg * SEGJ;
#pragma unroll 4
    for (int j = j0; j < j0 + SEGJ; ++j) {
        float4 pj = pos[j];
        float dx = pi.x - pj.x;
        float dy = pi.y - pj.y;
        float dz = pi.z - pj.z;
        // exact np order: (dx*dx + dy*dy) + dz*dz, each op rounded, no fma
        float d2 = __fadd_rn(__fadd_rn(__fmul_rn(dx, dx), __fmul_rn(dy, dy)),
                             __fmul_rn(dz, dz));
        if (d2 < R2c && j != i) {
            if (cnt < SEGCAP) jb[threadIdx.x][cnt] = (unsigned short)j;
            cnt++;
        }
    }
    if (cnt > SEGCAP) cnt = SEGCAP;
    degs[threadIdx.x] = cnt;
    __syncthreads();
    // prefix over lower segments of this node -> compact, j-ascending
    int off = 0;
    for (int s = 0; s < seg; ++s) off += degs[s * 32 + node];
    int base = gi * MAXNBR + off;
    for (int k = 0; k < cnt; ++k) nbr[base + k] = (int)jb[threadIdx.x][k];
    if (seg == NSEG - 1) {
        int tot = off + cnt;
        cntN[gi] = tot;
        float di = (float)(1.0 / sqrt((double)(1 + tot)));  // exact rsqrt
        dinv[gi] = di;
        const float* srow = sb + (size_t)i * 6;
        float* xr = xs0 + (size_t)gi * 6;
#pragma unroll
        for (int c = 0; c < 6; ++c) xr[c] = di * srow[c];
    }
}

// ---------------------------------------------------------------------------
// K2: layer 0 (6 -> 128). 512 blocks, 32 nodes x 8 ch-parts (16 ch each).
// ---------------------------------------------------------------------------
__global__ __launch_bounds__(256, 2) void k_l0(const float* __restrict__ xs0,
                                               const float* __restrict__ dinv,
                                               const int* __restrict__ nbr,
                                               const int* __restrict__ cntN,
                                               const float* __restrict__ W0,
                                               const float* __restrict__ b0,
                                               float* __restrict__ xs1) {
    int b = blockIdx.x & 7;
    int tile = blockIdx.x >> 3;
    int node = threadIdx.x >> 3;
    int part = threadIdx.x & 7;
    int i = tile * 32 + node;
    int gi = b * NN + i;
    float g[6];
    {
        const float* sr = xs0 + (size_t)gi * 6;
        float2 a0 = *(const float2*)sr;
        float2 a1 = *(const float2*)(sr + 2);
        float2 a2 = *(const float2*)(sr + 4);
        g[0] = a0.x; g[1] = a0.y; g[2] = a1.x; g[3] = a1.y; g[4] = a2.x; g[5] = a2.y;
    }
    int cnt = cntN[gi];
    const int* nb = nbr + gi * MAXNBR;
    for (int k = 0; k < cnt; ++k) {
        int j = nb[k];
        const float* xr = xs0 + (size_t)(b * NN + j) * 6;
        float2 v0 = *(const float2*)xr;
        float2 v1 = *(const float2*)(xr + 2);
        float2 v2 = *(const float2*)(xr + 4);
        g[0] += v0.x; g[1] += v0.y; g[2] += v1.x;
        g[3] += v1.y; g[4] += v2.x; g[5] += v2.y;
    }
    float di = dinv[gi];
#pragma unroll
    for (int c = 0; c < 6; ++c) g[c] *= di;
    int c0 = part * 16;
    float y[16];
#pragma unroll
    for (int r = 0; r < 4; ++r) {
        float4 bv = *(const float4*)(b0 + c0 + r * 4);
        y[r * 4 + 0] = bv.x; y[r * 4 + 1] = bv.y; y[r * 4 + 2] = bv.z; y[r * 4 + 3] = bv.w;
    }
#pragma unroll
    for (int k = 0; k < 6; ++k) {
        float u = g[k];
        const float* wr = W0 + k * HH + c0;
#pragma unroll
        for (int r = 0; r < 4; ++r) {
            float4 w = *(const float4*)(wr + r * 4);
            y[r * 4 + 0] = fmaf(u, w.x, y[r * 4 + 0]);
            y[r * 4 + 1] = fmaf(u, w.y, y[r * 4 + 1]);
            y[r * 4 + 2] = fmaf(u, w.z, y[r * 4 + 2]);
            y[r * 4 + 3] = fmaf(u, w.w, y[r * 4 + 3]);
        }
    }
    float* xo = xs1 + (size_t)gi * HH + c0;
#pragma unroll
    for (int r = 0; r < 4; ++r) {
        float4 v;
        v.x = di * fmaxf(y[r * 4 + 0], 0.f);
        v.y = di * fmaxf(y[r * 4 + 1], 0.f);
        v.z = di * fmaxf(y[r * 4 + 2], 0.f);
        v.w = di * fmaxf(y[r * 4 + 3], 0.f);
        *(float4*)(xo + r * 4) = v;
    }
}

// ---------------------------------------------------------------------------
// 128->128 layers: gather u-tile to LDS, GEMM with double-buffered 32-row
// W LDS panels. CHANNEL-INTERLEAVED ownership: thread cb owns channels
// {cb*4..+3} and {64+cb*4..+3} -> W reads are stride-4-word across lanes
// (consecutive float4s, 2 addrs/bank + broadcast = conflict-free), vs R3's
// cb*8 stride-8 pattern that cost 2.3e6 conflict-cycles/dispatch.
// Pure permutation of channel->thread map; per-channel FP sums unchanged.
// ---------------------------------------------------------------------------
__device__ __forceinline__ void gather_into_lds(const float* __restrict__ xin,
                                                const float* __restrict__ dinv,
                                                const int* __restrict__ nbr,
                                                const int* __restrict__ cntN,
                                                int b, int tile,
                                                float (*uS)[HH + 4]) {
    const int node = threadIdx.x >> 3;   // 0..31
    const int part = threadIdx.x & 7;    // 16 ch each
    const int i = tile * 32 + node;
    const int gi = b * NN + i;
    const int c0 = part * 16;
    float acc[16];
    const float* xs = xin + (size_t)gi * HH + c0;
#pragma unroll
    for (int r = 0; r < 4; ++r) *(float4*)&acc[r * 4] = *(const float4*)(xs + r * 4);
    const int cnt = cntN[gi];
    const int* nb = nbr + gi * MAXNBR;
    for (int k = 0; k < cnt; ++k) {
        const int j = nb[k];
        const float* xr = xin + (size_t)(b * NN + j) * HH + c0;
#pragma unroll
        for (int r = 0; r < 4; ++r) {
            float v[4];
            *(float4*)v = *(const float4*)(xr + r * 4);
            acc[r * 4 + 0] += v[0]; acc[r * 4 + 1] += v[1];
            acc[r * 4 + 2] += v[2]; acc[r * 4 + 3] += v[3];
        }
    }
    const float di = dinv[gi];
#pragma unroll
    for (int r = 0; r < 4; ++r) {
        float4 o;
        o.x = acc[r * 4 + 0] * di; o.y = acc[r * 4 + 1] * di;
        o.z = acc[r * 4 + 2] * di; o.w = acc[r * 4 + 3] * di;
        *(float4*)&uS[node][c0 + r * 4] = o;
    }
}

// GEMM over one 32-row W panel in LDS. Thread owns 2 nodes x channels
// {cA..cA+3, cA+64..cA+67}. y[0..3] = low group, y[4..7] = high group.
__device__ __forceinline__ void gemm_panel(const float (*uS)[HH + 4],
                                           const float* __restrict__ wbuf,
                                           int p, int n0, int cA,
                                           float y0[8], float y1[8]) {
#pragma unroll 2
    for (int r = 0; r < 32; r += 4) {
        float ua[4], ub[4];
        *(float4*)ua = *(const float4*)(&uS[n0][p * 32 + r]);
        *(float4*)ub = *(const float4*)(&uS[n0 + 1][p * 32 + r]);
        const float* wrow = wbuf + r * HH + cA;
#pragma unroll
        for (int q = 0; q < 4; ++q) {
            float4 wa = *(const float4*)(wrow + q * HH);        // ch cA..cA+3
            float4 wb = *(const float4*)(wrow + q * HH + 64);   // ch cA+64..
            float u0 = ua[q], u1 = ub[q];
            y0[0] = fmaf(u0, wa.x, y0[0]); y0[1] = fmaf(u0, wa.y, y0[1]);
            y0[2] = fmaf(u0, wa.z, y0[2]); y0[3] = fmaf(u0, wa.w, y0[3]);
            y0[4] = fmaf(u0, wb.x, y0[4]); y0[5] = fmaf(u0, wb.y, y0[5]);
            y0[6] = fmaf(u0, wb.z, y0[6]); y0[7] = fmaf(u0, wb.w, y0[7]);
            y1[0] = fmaf(u1, wa.x, y1[0]); y1[1] = fmaf(u1, wa.y, y1[1]);
            y1[2] = fmaf(u1, wa.z, y1[2]); y1[3] = fmaf(u1, wa.w, y1[3]);
            y1[4] = fmaf(u1, wb.x, y1[4]); y1[5] = fmaf(u1, wb.y, y1[5]);
            y1[6] = fmaf(u1, wb.z, y1[6]); y1[7] = fmaf(u1, wb.w, y1[7]);
        }
    }
}

// K3: middle layer (layer 1): xs_out = dinv * relu(u @ W + b)
__global__ __launch_bounds__(256, 3) void k_mid(const float* __restrict__ xin,
                                                const float* __restrict__ dinv,
                                                const int* __restrict__ nbr,
                                                const int* __restrict__ cntN,
                                                const float* __restrict__ W,
                                                const float* __restrict__ bias,
                                                float* __restrict__ xout) {
    __shared__ __align__(16) float uS[32][HH + 4];
    __shared__ __align__(16) float wS[2][32 * HH];
    int b = blockIdx.x & 7;
    int tile = blockIdx.x >> 3;
    int t = threadIdx.x;
    const float4* Wf4 = (const float4*)W;
    float4 wreg[4];
#pragma unroll
    for (int q = 0; q < 4; ++q) wreg[q] = Wf4[t + q * 256];   // panel 0
    gather_into_lds(xin, dinv, nbr, cntN, b, tile, uS);
    {
        float4* ws4 = (float4*)wS[0];
#pragma unroll
        for (int q = 0; q < 4; ++q) ws4[t + q * 256] = wreg[q];
    }
    __syncthreads();
    int cb = t & 15, ng = t >> 4;
    int n0 = ng * 2, cA = cb * 4;
    float y0[8], y1[8];
    {
        float4 bv0 = *(const float4*)(bias + cA);
        float4 bv1 = *(const float4*)(bias + cA + 64);
        y0[0] = bv0.x; y0[1] = bv0.y; y0[2] = bv0.z; y0[3] = bv0.w;
        y0[4] = bv1.x; y0[5] = bv1.y; y0[6] = bv1.z; y0[7] = bv1.w;
#pragma unroll
        for (int r = 0; r < 8; ++r) y1[r] = y0[r];
    }
#pragma unroll
    for (int p = 0; p < 4; ++p) {
        if (p < 3) {
#pragma unroll
            for (int q = 0; q < 4; ++q) wreg[q] = Wf4[(p + 1) * 1024 + t + q * 256];
        }
        gemm_panel(uS, wS[p & 1], p, n0, cA, y0, y1);
        if (p < 3) {
            float4* ws4 = (float4*)wS[1 - (p & 1)];
#pragma unroll
            for (int q = 0; q < 4; ++q) ws4[t + q * 256] = wreg[q];
            __syncthreads();
        }
    }
    int g0 = b * NN + tile * 32 + n0;
    float di0 = dinv[g0], di1 = dinv[g0 + 1];
    float* o0 = xout + (size_t)g0 * HH + cA;
    float* o1 = o0 + HH;
    float4 va, vb;
    va.x = di0 * fmaxf(y0[0], 0.f); va.y = di0 * fmaxf(y0[1], 0.f);
    va.z = di0 * fmaxf(y0[2], 0.f); va.w = di0 * fmaxf(y0[3], 0.f);
    vb.x = di0 * fmaxf(y0[4], 0.f); vb.y = di0 * fmaxf(y0[5], 0.f);
    vb.z = di0 * fmaxf(y0[6], 0.f); vb.w = di0 * fmaxf(y0[7], 0.f);
    *(float4*)o0 = va; *(float4*)(o0 + 64) = vb;
    va.x = di1 * fmaxf(y1[0], 0.f); va.y = di1 * fmaxf(y1[1], 0.f);
    va.z = di1 * fmaxf(y1[2], 0.f); va.w = di1 * fmaxf(y1[3], 0.f);
    vb.x = di1 * fmaxf(y1[4], 0.f); vb.y = di1 * fmaxf(y1[5], 0.f);
    vb.z = di1 * fmaxf(y1[6], 0.f); vb.w = di1 * fmaxf(y1[7], 0.f);
    *(float4*)o1 = va; *(float4*)(o1 + 64) = vb;
}

// K4: layer 2 + FC head + state update + output write.
// After the last panel, wS[0] is reused as y3[32][128] and wS[1] as wfcS.
__global__ __launch_bounds__(256, 3) void k_last(const float* __restrict__ xin,
                                                 const float* __restrict__ dinv,
                                                 const int* __restrict__ nbr,
                                                 const int* __restrict__ cntN,
                                                 const float* __restrict__ W2,
                                                 const float* __restrict__ b2,
                                                 const float* __restrict__ Wfc,
                                                 const float* __restrict__ bfc,
                                                 const float* __restrict__ padding,
                                                 float* __restrict__ states,
                                                 float* __restrict__ outt) {
    __shared__ __align__(16) float uS[32][HH + 4];
    __shared__ __align__(16) float wS[2][32 * HH];
    int b = blockIdx.x & 7;
    int tile = blockIdx.x >> 3;
    int t = threadIdx.x;
    const float4* Wf4 = (const float4*)W2;
    float4 wreg[4];
#pragma unroll
    for (int q = 0; q < 4; ++q) wreg[q] = Wf4[t + q * 256];
    gather_into_lds(xin, dinv, nbr, cntN, b, tile, uS);
    {
        float4* ws4 = (float4*)wS[0];
#pragma unroll
        for (int q = 0; q < 4; ++q) ws4[t + q * 256] = wreg[q];
    }
    __syncthreads();
    int cb = t & 15, ng = t >> 4;
    int n0 = ng * 2, cA = cb * 4;
    float y0[8], y1[8];
    {
        float4 bv0 = *(const float4*)(b2 + cA);
        float4 bv1 = *(const float4*)(b2 + cA + 64);
        y0[0] = bv0.x; y0[1] = bv0.y; y0[2] = bv0.z; y0[3] = bv0.w;
        y0[4] = bv1.x; y0[5] = bv1.y; y0[6] = bv1.z; y0[7] = bv1.w;
#pragma unroll
        for (int r = 0; r < 8; ++r) y1[r] = y0[r];
    }
#pragma unroll
    for (int p = 0; p < 4; ++p) {
        if (p < 3) {
#pragma unroll
            for (int q = 0; q < 4; ++q) wreg[q] = Wf4[(p + 1) * 1024 + t + q * 256];
        }
        gemm_panel(uS, wS[p & 1], p, n0, cA, y0, y1);
        if (p < 3) {
            float4* ws4 = (float4*)wS[1 - (p & 1)];
#pragma unroll
            for (int q = 0; q < 4; ++q) ws4[t + q * 256] = wreg[q];
            __syncthreads();
        }
    }
    __syncthreads();   // all panel reads done; reuse wS
    float* y3  = wS[0];   // [32][HH]
    float* wfc = wS[1];   // HH*6 floats
#pragma unroll
    for (int q = 0; q < 3; ++q) wfc[t + q * 256] = Wfc[t + q * 256];
    {
        float4 v;
        v.x = fmaxf(y0[0], 0.f); v.y = fmaxf(y0[1], 0.f);
        v.z = fmaxf(y0[2], 0.f); v.w = fmaxf(y0[3], 0.f);
        *(float4*)&y3[n0 * HH + cA] = v;
        v.x = fmaxf(y0[4], 0.f); v.y = fmaxf(y0[5], 0.f);
        v.z = fmaxf(y0[6], 0.f); v.w = fmaxf(y0[7], 0.f);
        *(float4*)&y3[n0 * HH + cA + 64] = v;
        v.x = fmaxf(y1[0], 0.f); v.y = fmaxf(y1[1], 0.f);
        v.z = fmaxf(y1[2], 0.f); v.w = fmaxf(y1[3], 0.f);
        *(float4*)&y3[(n0 + 1) * HH + cA] = v;
        v.x = fmaxf(y1[4], 0.f); v.y = fmaxf(y1[5], 0.f);
        v.z = fmaxf(y1[6], 0.f); v.w = fmaxf(y1[7], 0.f);
        *(float4*)&y3[(n0 + 1) * HH + cA + 64] = v;
    }
    __syncthreads();
    if (t < 192) {
        int n = t / 6;
        int c = t - n * 6;
        float r = bfc[c];
        for (int k = 0; k < HH; k += 4) {
            float yv[4];
            *(float4*)yv = *(const float4*)&y3[n * HH + k];
            r = fmaf(yv[0], wfc[(k + 0) * 6 + c], r);
            r = fmaf(yv[1], wfc[(k + 1) * 6 + c], r);
            r = fmaf(yv[2], wfc[(k + 2) * 6 + c], r);
            r = fmaf(yv[3], wfc[(k + 3) * 6 + c], r);
        }
        int i = tile * 32 + n;
        int gi = b * NN + i;
        float pv = padding[b * NN + i];   // all-ones in this setup
        float s = states[(size_t)gi * 6 + c] + r * pv;
        states[(size_t)gi * 6 + c] = s;
        if (c < 3) outt[(size_t)b * OUT_BSTRIDE + i * 3 + c] = s;
    }
}

// ---------------------------------------------------------------------------
extern "C" void kernel_launch(void* const* d_in, const int* in_sizes, int n_in,
                              void* d_out, int out_size, void* d_ws, size_t ws_size,
                              hipStream_t stream) {
    (void)in_sizes; (void)n_in; (void)out_size; (void)ws_size;
    const float* points  = (const float*)d_in[0];
    const float* padding = (const float*)d_in[5];
    const float* W0  = (const float*)d_in[6];
    const float* b0  = (const float*)d_in[7];
    const float* W1  = (const float*)d_in[8];
    const float* b1  = (const float*)d_in[9];
    const float* W2  = (const float*)d_in[10];
    const float* b2  = (const float*)d_in[11];
    const float* Wfc = (const float*)d_in[12];
    const float* bfc = (const float*)d_in[13];
    float* out = (float*)d_out;

    // workspace carve-up (~24 MB)
    float* ws     = (float*)d_ws;
    float* states = ws;                       // BB*NN*6
    float* xs0    = states + BB * NN * 6;     // BB*NN*6
    float* xs1    = xs0 + BB * NN * 6;        // BB*NN*HH
    float* xs2    = xs1 + BB * NN * HH;       // BB*NN*HH
    float* dinvp  = xs2 + BB * NN * HH;       // BB*NN
    int*   nbr    = (int*)(dinvp + BB * NN);  // BB*NN*MAXNBR
    int*   cntN   = nbr + BB * NN * MAXNBR;   // BB*NN

    k_init<<<(BB * NN) / 256, 256, 0, stream>>>(points, states, out);
    for (int t = 0; t < PREDL; ++t) {
        k_adj<<<512, 256, 0, stream>>>(states, xs0, dinvp, nbr, cntN);
        k_l0<<<512, 256, 0, stream>>>(xs0, dinvp, nbr, cntN, W0, b0, xs1);
        k_mid<<<512, 256, 0, stream>>>(xs1, dinvp, nbr, cntN, W1, b1, xs2);
        k_last<<<512, 256, 0, stream>>>(xs2, dinvp, nbr, cntN, W2, b2, Wfc, bfc,
                                        padding, states,
                                        out + (size_t)(t + 1) * TSTRIDE);
    }
}